// Round 1
// baseline (319.669 us; speedup 1.0000x reference)
//
#include <hip/hip_runtime.h>

#define DEV __device__ __forceinline__

typedef __attribute__((ext_vector_type(8))) short short8;
typedef __attribute__((ext_vector_type(4))) float f32x4;
typedef unsigned short u16;

struct Ptrs { const void* p[32]; };

// ---------------- compile-time problem constants ----------------
constexpr int N_TOK = 65536;
constexpr int cK  [5] = {4,4,5,6,6};              // feats per expert
constexpr int cK1 [5] = {256,256,320,384,384};    // K*D
constexpr int cKT [5] = {8,8,10,12,12};           // K1/32
constexpr int cN2 [5] = {264,264,256,256,256};    // head out cols
constexpr int cNT [5] = {17,17,16,16,16};         // ceil(N2/16)
constexpr int cC0 [5] = {0,264,528,784,1040};     // output col offset
// register sources: 0:A 1:X 2:Y 3:SP 4:P 5:PCH 6:PCL 7:Op 8:Val 9:carry(P&1)
constexpr int cKID[5][6] = {{0,8,9,7,0,0},{0,8,9,7,0,0},{0,1,2,8,7,0},
                            {5,6,4,8,3,7},{0,1,3,4,8,7}};
// bf16 workspace element offsets
constexpr int cEOFF[5] = {0,65536,131072,212992,311296};      // emb, tot 409600
constexpr int cWOFF[5] = {0,131072,262144,425984,622592};     // W1t, tot 819200
constexpr int cHOFF[5] = {0,139264,278528,417792,557056};     // headT, tot 696320
constexpr int EMB_TOT = 409600, W1_TOT = 819200, HEAD_TOT = 696320;
constexpr int PREP_TOT = EMB_TOT + W1_TOT + HEAD_TOT;         // 1,925,120

// ws byte offsets
constexpr size_t WS_COUNTS = 0;
constexpr size_t WS_BUCKET = 256;
constexpr size_t WS_EMB    = 256 + (size_t)5 * N_TOK * 4;     // 1,310,976
constexpr size_t WS_W1T    = WS_EMB + (size_t)EMB_TOT * 2;    // 2,130,176
constexpr size_t WS_HT     = WS_W1T + (size_t)W1_TOT * 2;     // 3,768,576

constexpr int LDS_FBUF_B = 64 * 392 * 2;   // max [64][K1max+8] bf16
constexpr int LDS_HBUF_B = 64 * 520 * 2;   // [64][512+8] bf16
constexpr int LDS_BYTES  = LDS_FBUF_B + LDS_HBUF_B + 64*4 + 64*6*4; // 118,528

DEV u16 f2bf(float f) {              // RNE f32 -> bf16 (finite inputs)
  unsigned u = __builtin_bit_cast(unsigned, f);
  u += 0x7FFFu + ((u >> 16) & 1u);
  return (u16)(u >> 16);
}

DEV float gelu_f(float x) {          // tanh-approx gelu (JAX default)
  float u = 0.7978845608028654f * x * (1.0f + 0.044715f * x * x);
  float t2 = fminf(fmaxf(2.0f * u, -30.0f), 30.0f);
  float e = __expf(t2);
  float th = (e - 1.0f) / (e + 1.0f);
  return 0.5f * x * (1.0f + th);
}

// ---------------- prep: f32 -> bf16 (+ transposes, head packing) ----------------
__global__ __launch_bounds__(256) void prep_kernel(Ptrs in, u16* embB, u16* w1tB, u16* hTB) {
  int idx = blockIdx.x * 256 + threadIdx.x;   // grid sized exactly PREP_TOT/256
  if (idx < EMB_TOT) {
    int e = 0, off = idx;
    while (off >= cK[e] * 16384) { off -= cK[e] * 16384; ++e; }
    const float* src = (const float*)in.p[10 + 3*e];
    embB[cEOFF[e] + off] = f2bf(src[off]);
  } else if (idx < EMB_TOT + W1_TOT) {
    int off = idx - EMB_TOT;
    int e = 0;
    while (off >= 512 * cK1[e]) { off -= 512 * cK1[e]; ++e; }
    int K1 = cK1[e];
    int n = off / K1, k = off - n * K1;       // W1t[n][k] = W1[k][n]
    const float* w1 = (const float*)in.p[11 + 3*e];
    w1tB[cWOFF[e] + off] = f2bf(w1[k * 512 + n]);
  } else {
    int off = idx - (EMB_TOT + W1_TOT);
    int e = off / 139264, r = off - e * 139264;
    int n = r >> 9, k = r & 511;              // headT[n][k], n in [0,272)
    float v = 0.0f;
    if (e < 2) {
      if (n < 256)       v = ((const float*)in.p[25 + 2*e])[k * 256 + n];
      else if (n < 264)  v = ((const float*)in.p[26 + 2*e])[k * 8 + (n - 256)];
    } else {
      if (n < 256)       v = ((const float*)in.p[29 + (e - 2)])[k * 256 + n];
    }
    hTB[cHOFF[e] + r] = f2bf(v);
  }
}

// ---------------- bucket tokens by fu ----------------
__global__ __launch_bounds__(256) void bucket_kernel(const int* Op, const int* fu_map,
                                                     int* counts, int* buckets) {
  __shared__ int lc[5], lb[5];
  int tid = threadIdx.x;
  if (tid < 5) lc[tid] = 0;
  __syncthreads();
  int t = blockIdx.x * 256 + tid;             // grid = N/256 exactly
  int fu = fu_map[Op[t]];
  int lp = atomicAdd(&lc[fu], 1);
  __syncthreads();
  if (tid < 5) lb[tid] = atomicAdd(&counts[tid], lc[tid]);
  __syncthreads();
  buckets[fu * N_TOK + lb[fu] + lp] = t;
}

// ---------------- fused expert: gather -> GEMM1 -> gelu -> GEMM2 -> out ----------------
template<int E>
DEV void expert_body(const Ptrs& in, const int* counts, const int* buckets,
                     const u16* embB, const u16* w1tB, const u16* hTB,
                     float* out, char* smem) {
  constexpr int K1 = cK1[E], KT = cKT[E], N2 = cN2[E], C0 = cC0[E];
  constexpr int NT = cNT[E], KE = cK[E];
  constexpr int FP = K1 + 8;     // fbuf pitch (bf16 elems)
  constexpr int HP = 520;        // hbuf pitch

  u16* fbuf = (u16*)smem;
  u16* hbuf = (u16*)(smem + LDS_FBUF_B);
  int* tokb = (int*)(smem + LDS_FBUF_B + LDS_HBUF_B);
  int* idsb = tokb + 64;

  const int tid  = threadIdx.x;
  const int tile = blockIdx.x;
  const int count = counts[E];
  if (tile * 64 >= count) return;
  const int vr = (count - tile * 64 < 64) ? (count - tile * 64) : 64;

  if (tid < 64) {
    int row = tile * 64 + tid;
    int t = (row < count) ? buckets[E * N_TOK + row] : 0;
    tokb[tid] = (row < count) ? t : -1;
    #pragma unroll
    for (int k = 0; k < KE; ++k) {
      int s = cKID[E][k];
      int v = (s == 9) ? (((const int*)in.p[4])[t] & 1)
                       : ((const int*)in.p[s])[t];
      idsb[tid * 6 + k] = v;
    }
  }
  __syncthreads();

  // zero-fill inactive output columns for valid rows (single-pass full-row write)
  {
    constexpr int ZC  = (1296 - N2) / 4;    // float4s of zeros per row
    constexpr int ZLO = C0 / 4;
    constexpr int ZHI = (C0 + N2) / 4;
    int tot = vr * ZC;
    for (int i = tid; i < tot; i += 256) {
      int r = i / ZC, c = i - r * ZC;
      size_t t = (size_t)tokb[r];
      int col4 = (c < ZLO) ? c : (c - ZLO + ZHI);
      *(float4*)(out + t * 1296 + col4 * 4) = make_float4(0.f, 0.f, 0.f, 0.f);
    }
  }

  // gather f (bf16) into LDS: fbuf[row][k*64 + d]
  {
    constexpr int CPR = KE * 8;   // 16B chunks per row
    const u16* embE = embB + cEOFF[E];
    for (int i = tid; i < 64 * CPR; i += 256) {
      int r = i / CPR, c = i - r * CPR;
      int k = c >> 3, cc = c & 7;
      int id = idsb[r * 6 + k];
      *(short8*)(fbuf + r * FP + k * 64 + cc * 8) =
        *(const short8*)(embE + ((k * 256 + id) * 64) + cc * 8);
    }
  }
  __syncthreads();

  const int lane = tid & 63, wave = tid >> 6;
  const int l15 = lane & 15, lq = lane >> 4;
  const u16* w1e = w1tB + cWOFF[E];
  const float* b1 = (const float*)in.p[12 + 3 * E];

  // GEMM1: h[64][512] = gelu(f @ W1 + b1); wave w owns cols [w*128, w*128+128)
  #pragma unroll 1
  for (int half = 0; half < 2; ++half) {
    f32x4 acc[4][4];
    const f32x4 z = {0.f, 0.f, 0.f, 0.f};
    #pragma unroll
    for (int m = 0; m < 4; ++m)
      #pragma unroll
      for (int nt = 0; nt < 4; ++nt) acc[m][nt] = z;

    for (int kt = 0; kt < KT; ++kt) {
      short8 a[4];
      #pragma unroll
      for (int m = 0; m < 4; ++m)
        a[m] = *(const short8*)(fbuf + (m * 16 + l15) * FP + kt * 32 + lq * 8);
      #pragma unroll
      for (int nt = 0; nt < 4; ++nt) {
        int n0 = wave * 128 + half * 64 + nt * 16;
        short8 b = *(const short8*)(w1e + (n0 + l15) * K1 + kt * 32 + lq * 8);
        #pragma unroll
        for (int m = 0; m < 4; ++m)
          acc[m][nt] = __builtin_amdgcn_mfma_f32_16x16x32_bf16(a[m], b, acc[m][nt], 0, 0, 0);
      }
    }
    #pragma unroll
    for (int nt = 0; nt < 4; ++nt) {
      int col = wave * 128 + half * 64 + nt * 16 + l15;
      float b1v = b1[col];
      #pragma unroll
      for (int m = 0; m < 4; ++m)
        #pragma unroll
        for (int r = 0; r < 4; ++r) {
          int row = m * 16 + lq * 4 + r;
          hbuf[row * HP + col] = f2bf(gelu_f(acc[m][nt][r] + b1v));
        }
    }
  }
  __syncthreads();

  // GEMM2: out_tile = h @ head; wave w takes n-tiles {w, w+4, w+8, ...}
  const u16* hTe = hTB + cHOFF[E];
  f32x4 acc2[4][5];
  {
    const f32x4 z = {0.f, 0.f, 0.f, 0.f};
    #pragma unroll
    for (int m = 0; m < 4; ++m)
      #pragma unroll
      for (int j = 0; j < 5; ++j) acc2[m][j] = z;
  }
  for (int kt = 0; kt < 16; ++kt) {
    short8 a[4];
    #pragma unroll
    for (int m = 0; m < 4; ++m)
      a[m] = *(const short8*)(hbuf + (m * 16 + l15) * HP + kt * 32 + lq * 8);
    #pragma unroll
    for (int j = 0; j < 5; ++j) {
      int nt = wave + 4 * j;
      if (nt >= NT) break;
      short8 b = *(const short8*)(hTe + (nt * 16 + l15) * 512 + kt * 32 + lq * 8);
      #pragma unroll
      for (int m = 0; m < 4; ++m)
        acc2[m][j] = __builtin_amdgcn_mfma_f32_16x16x32_bf16(a[m], b, acc2[m][j], 0, 0, 0);
    }
  }
  #pragma unroll
  for (int j = 0; j < 5; ++j) {
    int nt = wave + 4 * j;
    if (nt >= NT) break;
    int coln = nt * 16 + l15;
    if (coln < N2) {
      #pragma unroll
      for (int m = 0; m < 4; ++m)
        #pragma unroll
        for (int r = 0; r < 4; ++r) {
          int row = m * 16 + lq * 4 + r;
          int t = tokb[row];
          if (t >= 0) out[(size_t)t * 1296 + C0 + coln] = acc2[m][j][r];
        }
    }
  }
}

__global__ __launch_bounds__(256, 1) void moe_kernel(Ptrs in, const int* counts, const int* buckets,
                                                     const u16* embB, const u16* w1tB, const u16* hTB,
                                                     float* out) {
  extern __shared__ char smem[];
  switch (blockIdx.y) {
    case 0: expert_body<0>(in, counts, buckets, embB, w1tB, hTB, out, smem); break;
    case 1: expert_body<1>(in, counts, buckets, embB, w1tB, hTB, out, smem); break;
    case 2: expert_body<2>(in, counts, buckets, embB, w1tB, hTB, out, smem); break;
    case 3: expert_body<3>(in, counts, buckets, embB, w1tB, hTB, out, smem); break;
    case 4: expert_body<4>(in, counts, buckets, embB, w1tB, hTB, out, smem); break;
  }
}

extern "C" void kernel_launch(void* const* d_in, const int* in_sizes, int n_in,
                              void* d_out, int out_size, void* d_ws, size_t ws_size,
                              hipStream_t stream) {
  char* ws = (char*)d_ws;
  int* counts  = (int*)(ws + WS_COUNTS);
  int* buckets = (int*)(ws + WS_BUCKET);
  u16* embB    = (u16*)(ws + WS_EMB);
  u16* w1tB    = (u16*)(ws + WS_W1T);
  u16* hTB     = (u16*)(ws + WS_HT);

  Ptrs P;
  for (int i = 0; i < 32; ++i) P.p[i] = d_in[i];

  hipMemsetAsync(counts, 0, 5 * sizeof(int), stream);
  prep_kernel<<<PREP_TOT / 256, 256, 0, stream>>>(P, embB, w1tB, hTB);
  bucket_kernel<<<N_TOK / 256, 256, 0, stream>>>((const int*)d_in[7], (const int*)d_in[9],
                                                 counts, buckets);
  dim3 grid(1024, 5, 1);
  moe_kernel<<<grid, 256, LDS_BYTES, stream>>>(P, counts, buckets, embB, w1tB, hTB,
                                               (float*)d_out);
}